// Round 17
// baseline (70.227 us; speedup 1.0000x reference)
//
#include <hip/hip_runtime.h>

typedef __bf16 bf16x8 __attribute__((ext_vector_type(8)));
typedef __bf16 bf16x4 __attribute__((ext_vector_type(4)));
typedef __bf16 bf16x2 __attribute__((ext_vector_type(2)));
typedef float  f32x4  __attribute__((ext_vector_type(4)));

constexpr int Bc = 2, Sc = 256, Kc = 32, Tc = 8192, Dc = 1024, Vc = 6144, NLc = 4;
constexpr int NPANEL = (Tc * Bc) / 128;   // 128 chunks (64 frames x both batches)
constexpr int UTS = NLc * Dc;             // u_tok_all row stride (4096)

__device__ __forceinline__ void gload16(const void* g, void* l) {
    __builtin_amdgcn_global_load_lds(
        (const __attribute__((address_space(1))) unsigned int*)g,
        (__attribute__((address_space(3))) unsigned int*)l,
        16, 0, 0);
}

// bijective XCD-aware block swizzle (m204 variant)
__device__ __forceinline__ int xcd_swz(int lin, int nwg) {
    int q = nwg >> 3, r = nwg & 7;
    int x = lin & 7, o = lin >> 3;
    int base = (x < r) ? x * (q + 1) : r * (q + 1) + (x - r) * q;
    return base + o;
}

// OR of n flag arrays (stride NPANEL) at chunk p
__device__ __forceinline__ bool gate_or(const int* f, int n, int p) {
    bool g = false;
    for (int j = 0; j < n; ++j) g = g || (f[j * NPANEL + p] != 0);
    return g;
}

// ---------------------------------------------------------------------------
// GEMM: C[M][N] = A[M][K](bf16 rm) x BT[N][K](bf16 rm), BMxBN tile, BK deep,
// 4 waves (2x2), mfma 16x16x32, swizzled LDS via pre-swizzled global source
// + linear-dest global_load_lds (width 16).
// EPI 0: Cout=acc   EPI 2: Cout=acc+bias[col]   EPI 3: outb=bf16(acc)
// ---------------------------------------------------------------------------
template<int EPI, int BM, int BN, int BK>
__global__ __launch_bounds__(256)
void gemm_bt(const __bf16* __restrict__ A, const __bf16* __restrict__ BT,
             int M, int N, int Kd,
             float* __restrict__ Cout, __bf16* __restrict__ outb,
             const float* __restrict__ bias)
{
    constexpr int MI = BM / 32, NI = BN / 32;
    constexpr int KCH  = BK / 8;
    constexpr int SWM  = KCH - 1;
    constexpr int ROWB = BK * 2;
    constexpr int CA = BM * KCH / 256;
    constexpr int CB = BN * KCH / 256;
    __shared__ char lds[(BM + BN) * ROWB];
    char* As = lds;
    char* Bs = lds + BM * ROWB;
    const int tid  = threadIdx.x;
    const int lane = tid & 63;
    const int wid  = tid >> 6;
    const int wm   = wid & 1, wn = wid >> 1;

    const int nwg = gridDim.x * gridDim.y;
    const int lin = blockIdx.y * gridDim.x + blockIdx.x;
    const int swz = xcd_swz(lin, nwg);
    const int bn  = (swz % gridDim.x) * BN;
    const int bm  = (swz / gridDim.x) * BM;

    const __bf16* asrc[CA];
#pragma unroll
    for (int i = 0; i < CA; ++i) {
        int chunk = i * 256 + tid;
        int row = chunk / KCH, kc = chunk % KCH;
        int kcs = kc ^ (row & SWM);
        asrc[i] = A + (size_t)(bm + row) * Kd + kcs * 8;
    }
    const __bf16* bsrc[CB];
#pragma unroll
    for (int i = 0; i < CB; ++i) {
        int chunk = i * 256 + tid;
        int row = chunk / KCH, kc = chunk % KCH;
        int kcs = kc ^ (row & SWM);
        bsrc[i] = BT + (size_t)(bn + row) * Kd + kcs * 8;
    }

    f32x4 acc[MI][NI] = {};

    for (int kt = 0; kt < Kd; kt += BK) {
#pragma unroll
        for (int i = 0; i < CA; ++i)
            gload16(asrc[i] + kt, As + (i * 256 + tid) * 16);
#pragma unroll
        for (int i = 0; i < CB; ++i)
            gload16(bsrc[i] + kt, Bs + (i * 256 + tid) * 16);
        __syncthreads();
#pragma unroll
        for (int kk = 0; kk < BK / 32; ++kk) {
            const int ko = kk * 64 + ((lane >> 4) << 4);
            bf16x8 af[MI], bfr[NI];
#pragma unroll
            for (int mi = 0; mi < MI; ++mi) {
                int row = wm * (BM / 2) + mi * 16 + (lane & 15);
                af[mi] = *(const bf16x8*)(As + row * ROWB +
                                          (ko ^ ((row & SWM) << 4)));
            }
#pragma unroll
            for (int ni = 0; ni < NI; ++ni) {
                int row = wn * (BN / 2) + ni * 16 + (lane & 15);
                bfr[ni] = *(const bf16x8*)(Bs + row * ROWB +
                                           (ko ^ ((row & SWM) << 4)));
            }
#pragma unroll
            for (int mi = 0; mi < MI; ++mi)
#pragma unroll
                for (int ni = 0; ni < NI; ++ni)
                    acc[mi][ni] = __builtin_amdgcn_mfma_f32_16x16x32_bf16(
                        af[mi], bfr[ni], acc[mi][ni], 0, 0, 0);
        }
        __syncthreads();
    }

    const int cc = lane & 15, cr = (lane >> 4) * 4;
#pragma unroll
    for (int mi = 0; mi < MI; ++mi) {
#pragma unroll
        for (int ni = 0; ni < NI; ++ni) {
            int gcol = bn + wn * (BN / 2) + ni * 16 + cc;
#pragma unroll
            for (int r = 0; r < 4; ++r) {
                int grow = bm + wm * (BM / 2) + mi * 16 + cr + r;
                size_t idx = (size_t)grow * N + gcol;
                float v = acc[mi][ni][r];
                if (EPI == 0)      Cout[idx] = v;
                else if (EPI == 2) Cout[idx] = v + bias[gcol];
                else               outb[idx] = (__bf16)v;
            }
        }
    }
}

// ---------------------------------------------------------------------------
// Hybrid: u-GEMM (512 blocks, 64x64 BK=256, latency-bound) co-tenant with the
// embed->bf16 cast (3072 streaming blocks). Cast result (emb_bf) is consumed
// only by the LM head, 4 kernel boundaries later — no race. GEMM blocks
// dispatch first; casts fill idle CUs/HBM behind them.
// ---------------------------------------------------------------------------
__global__ __launch_bounds__(256)
void gemm_u_cast(const __bf16* __restrict__ A, const __bf16* __restrict__ BT,
                 __bf16* __restrict__ outb,
                 const float* __restrict__ embed, __bf16* __restrict__ emb_bf)
{
    constexpr int BM = 64, BN = 64, BK = 256;
    constexpr int GX = UTS / BN;          // 64 N-tiles
    constexpr int NGEMM = GX * (Bc * Sc / BM);   // 512
    constexpr int KCH  = BK / 8, SWM = KCH - 1, ROWB = BK * 2;
    constexpr int CA = BM * KCH / 256, CB = BN * KCH / 256;
    const int tid = threadIdx.x;

    if (blockIdx.x >= NGEMM) {            // ---- cast role
        int idx = (blockIdx.x - NGEMM) * 256 + tid;
        const f32x4* pp = (const f32x4*)embed + (size_t)idx * 2;
        f32x4 v0 = pp[0], v1 = pp[1];
        bf16x8 o;
        o[0]=(__bf16)v0[0]; o[1]=(__bf16)v0[1]; o[2]=(__bf16)v0[2]; o[3]=(__bf16)v0[3];
        o[4]=(__bf16)v1[0]; o[5]=(__bf16)v1[1]; o[6]=(__bf16)v1[2]; o[7]=(__bf16)v1[3];
        ((bf16x8*)emb_bf)[idx] = o;
        return;
    }

    // ---- GEMM role (EPI=3 body)
    __shared__ char lds[(BM + BN) * ROWB];
    char* As = lds;
    char* Bs = lds + BM * ROWB;
    const int lane = tid & 63;
    const int wid  = tid >> 6;
    const int wm   = wid & 1, wn = wid >> 1;
    const int swz = xcd_swz(blockIdx.x, NGEMM);
    const int bn  = (swz % GX) * BN;
    const int bm  = (swz / GX) * BM;
    const int Kd  = Dc, N = UTS;

    const __bf16* asrc[CA];
#pragma unroll
    for (int i = 0; i < CA; ++i) {
        int chunk = i * 256 + tid;
        int row = chunk / KCH, kc = chunk % KCH;
        int kcs = kc ^ (row & SWM);
        asrc[i] = A + (size_t)(bm + row) * Kd + kcs * 8;
    }
    const __bf16* bsrc[CB];
#pragma unroll
    for (int i = 0; i < CB; ++i) {
        int chunk = i * 256 + tid;
        int row = chunk / KCH, kc = chunk % KCH;
        int kcs = kc ^ (row & SWM);
        bsrc[i] = BT + (size_t)(bn + row) * Kd + kcs * 8;
    }

    f32x4 acc[2][2] = {};
    for (int kt = 0; kt < Kd; kt += BK) {
#pragma unroll
        for (int i = 0; i < CA; ++i)
            gload16(asrc[i] + kt, As + (i * 256 + tid) * 16);
#pragma unroll
        for (int i = 0; i < CB; ++i)
            gload16(bsrc[i] + kt, Bs + (i * 256 + tid) * 16);
        __syncthreads();
#pragma unroll
        for (int kk = 0; kk < BK / 32; ++kk) {
            const int ko = kk * 64 + ((lane >> 4) << 4);
            bf16x8 af[2], bfr[2];
#pragma unroll
            for (int mi = 0; mi < 2; ++mi) {
                int row = wm * (BM / 2) + mi * 16 + (lane & 15);
                af[mi] = *(const bf16x8*)(As + row * ROWB +
                                          (ko ^ ((row & SWM) << 4)));
            }
#pragma unroll
            for (int ni = 0; ni < 2; ++ni) {
                int row = wn * (BN / 2) + ni * 16 + (lane & 15);
                bfr[ni] = *(const bf16x8*)(Bs + row * ROWB +
                                           (ko ^ ((row & SWM) << 4)));
            }
#pragma unroll
            for (int mi = 0; mi < 2; ++mi)
#pragma unroll
                for (int ni = 0; ni < 2; ++ni)
                    acc[mi][ni] = __builtin_amdgcn_mfma_f32_16x16x32_bf16(
                        af[mi], bfr[ni], acc[mi][ni], 0, 0, 0);
        }
        __syncthreads();
    }

    const int cc = lane & 15, cr = (lane >> 4) * 4;
#pragma unroll
    for (int mi = 0; mi < 2; ++mi)
#pragma unroll
        for (int ni = 0; ni < 2; ++ni) {
            int gcol = bn + wn * (BN / 2) + ni * 16 + cc;
#pragma unroll
            for (int r = 0; r < 4; ++r) {
                int grow = bm + wm * (BM / 2) + mi * 16 + cr + r;
                outb[(size_t)grow * N + gcol] = (__bf16)acc[mi][ni][r];
            }
        }
}

// ---------------------------------------------------------------------------
// Speculative whole-network scan (unchanged, proven r13-r16).
// ---------------------------------------------------------------------------
__global__ __launch_bounds__(1024)
void spec_scan(const __bf16* __restrict__ utok_base,
               const float* __restrict__ lbeta, const float* __restrict__ lvth,
               const float* __restrict__ htok, const float* __restrict__ alpha_p,
               const float* __restrict__ obeta, const float* __restrict__ ovth,
               __bf16* __restrict__ decoded, int* __restrict__ flags,
               int* __restrict__ dirtyAny)
{
    const int e = threadIdx.x;
    const int p = blockIdx.x;
    __shared__ int fm;
    if (e == 0) fm = 0;
    __syncthreads();

    unsigned mybits = 0;
#pragma unroll
    for (int l = 0; l < NLc; ++l) {
        const __bf16* utok = utok_base + (size_t)l * Dc;
        const float bet = lbeta[l * Dc + e], vt = lvth[l * Dc + e];
        float a = bet, S = 1.0f;
#pragma unroll
        for (int i = 0; i < 5; ++i) { S = S * (1.0f + a); a = a * a; }
        bool spike = false;
        for (int b = 0; b < Bc; ++b) {
            float V = 0.f;
            if (p > 0) {
#pragma unroll
                for (int ti = 0; ti < 2; ++ti) {
                    float u = (float)utok[((size_t)(2 * p - 2 + ti) * Bc + b) * UTS + e];
                    V = fmaf(a, V, u * S);
                }
            }
#pragma unroll
            for (int ti = 0; ti < 2; ++ti) {
                float u = (float)utok[((size_t)(2 * p + ti) * Bc + b) * UTS + e];
                float V1 = fmaf(bet, V, u);
                V = fmaf(a, V, u * S);
                spike = spike || (fmaxf(V1, V) >= vt);
            }
        }
        if (spike) mybits |= 1u << l;
    }
    unsigned wor = 0;
#pragma unroll
    for (int l = 0; l < NLc; ++l)
        if (__any(mybits & (1u << l))) wor |= 1u << l;
    if ((e & 63) == 0 && wor) atomicOr(&fm, (int)wor);
    __syncthreads();
    const int f = fm;
    if (e < NLc) flags[e * NPANEL + p] = (f >> e) & 1;
    if (e == 0 && f) atomicOr(dirtyAny, 1);

    const int w = e >> 6, lane = e & 63;
    const int ridx = w & 3, cq = w >> 2;
    const int s = 2 * p + (ridx >> 1), b = ridx & 1;
    const int gi = lane + 64 * cq;
    const float al = alpha_p[0];
    const f32x4 obet = ((const f32x4*)obeta)[gi];
    const f32x4 ovt  = ((const f32x4*)ovth)[gi];
    f32x4 oa = obet, oS = {1.f, 1.f, 1.f, 1.f};
#pragma unroll
    for (int i = 0; i < 5; ++i) {
#pragma unroll
        for (int c = 0; c < 4; ++c) { oS[c] *= 1.0f + oa[c]; oa[c] *= oa[c]; }
    }
    f32x4 V = {0, 0, 0, 0}, sum = {0, 0, 0, 0};
    for (int tk = (s >= 2 ? s - 2 : 0); tk < s; ++tk) {
        f32x4 h = ((const f32x4*)(htok + ((size_t)tk * Bc + b) * Dc))[gi];
#pragma unroll
        for (int c = 0; c < 4; ++c) V[c] = fmaf(oa[c], V[c], al * h[c] * oS[c]);
    }
    f32x4 h = ((const f32x4*)(htok + ((size_t)s * Bc + b) * Dc))[gi];
    for (int k = 0; k < Kc; ++k) {
#pragma unroll
        for (int c = 0; c < 4; ++c) {
            V[c] = fmaf(obet[c], V[c], al * h[c]);
            sum[c] += (V[c] >= ovt[c]) ? ovt[c] : 0.f;
        }
    }
    bf16x4 o;
#pragma unroll
    for (int c = 0; c < 4; ++c) o[c] = (__bf16)(sum[c] * (1.0f / 32.0f));
    ((bf16x4*)(decoded + ((size_t)b * Sc + s) * Dc))[gi] = o;
}

// ---------------------------------------------------------------------------
// Single-block gated fallback (unchanged, proven).
// ---------------------------------------------------------------------------
__global__ __launch_bounds__(1024)
void fallback_layers(const __bf16* __restrict__ utok_base,
                     const float* __restrict__ W_in, const float* __restrict__ W_out,
                     const float* __restrict__ lbeta, const float* __restrict__ lvth,
                     __bf16* __restrict__ dxA, __bf16* __restrict__ dxB,
                     int* __restrict__ flags_all, const int* __restrict__ dirty)
{
    if (dirty[0] == 0) return;
    const int e = threadIdx.x;
    __shared__ int fm;
    __shared__ __bf16 srow[Dc];
    const __bf16* dxR = dxA;
    __bf16*       dxW = dxB;

    for (int l = 0; l < NLc; ++l) {
        const __bf16* utok = utok_base + (size_t)l * Dc;
        const float*  Win  = W_in  + (size_t)l * Dc * Dc;
        const float*  Wout = W_out + (size_t)l * Dc * Dc;
        const float bet = lbeta[l * Dc + e], vt = lvth[l * Dc + e];
        float a = bet, S = 1.0f;
#pragma unroll
        for (int i = 0; i < 5; ++i) { S = S * (1.0f + a); a = a * a; }
        int* flags_l = flags_all + l * NPANEL;
        const __bf16 vtb = (__bf16)vt, zb = (__bf16)0.f;

        for (int p = 0; p < NPANEL; ++p) {
            const int t0 = p * 64;
            __syncthreads();
            if (e == 0) fm = 0;
            __syncthreads();
            const bool pd  = gate_or(flags_all, l, p);
            const bool pdw = (p > 0) && gate_or(flags_all, l, p - 1);

            auto ut = [&](int tk, int b) -> float {
                return (float)utok[((size_t)tk * Bc + b) * UTS + e];
            };
            auto du_at = [&](int t, int b) -> float {
                __syncthreads();
                srow[e] = dxR[((size_t)t * Bc + b) * Dc + e];
                __syncthreads();
                float acc = 0.f;
                for (int d = 0; d < Dc; ++d)
                    acc = fmaf((float)srow[d], Win[(size_t)d * Dc + e], acc);
                return acc;
            };

            bool spike = false;
            for (int b = 0; b < Bc; ++b) {
                float V = 0.f;
                if (p > 0) {
                    if (!pdw) {
                        for (int ti = 0; ti < 2; ++ti)
                            V = fmaf(a, V, ut(2 * p - 2 + ti, b) * S);
                    } else {
                        for (int t = t0 - 64; t < t0; ++t)
                            V = fmaf(bet, V, ut(t >> 5, b) + du_at(t, b));
                    }
                }
                if (!pd) {
                    for (int ti = 0; ti < 2; ++ti) {
                        const float u = ut(2 * p + ti, b);
                        float V1 = fmaf(bet, V, u);
                        V = fmaf(a, V, u * S);
                        spike = spike || (fmaxf(V1, V) >= vt);
                    }
                } else {
                    for (int k = 0; k < 64; ++k) {
                        V = fmaf(bet, V, ut((t0 + k) >> 5, b) + du_at(t0 + k, b));
                        spike = spike || (V >= vt);
                    }
                }
            }
            if (__any(spike) && (e & 63) == 0) atomicOr(&fm, 1);
            __syncthreads();
            const bool f = (fm != 0);
            if (e == 0) flags_l[p] = f ? 1 : 0;
            __syncthreads();

            if (!f) {
                if (pd) {
                    for (int rr = 0; rr < 128; ++rr)
                        dxW[(size_t)(t0 * Bc + rr) * Dc + e] =
                            dxR[(size_t)(t0 * Bc + rr) * Dc + e];
                }
                continue;
            }
            for (int b = 0; b < Bc; ++b) {
                float V = 0.f;
                if (p > 0) {
                    if (!pdw) {
                        for (int ti = 0; ti < 2; ++ti)
                            V = fmaf(a, V, ut(2 * p - 2 + ti, b) * S);
                    } else {
                        for (int t = t0 - 64; t < t0; ++t)
                            V = fmaf(bet, V, ut(t >> 5, b) + du_at(t, b));
                    }
                }
                for (int k = 0; k < 64; ++k) {
                    const int t = t0 + k;
                    float u = ut(t >> 5, b);
                    if (pd) u += du_at(t, b);
                    V = fmaf(bet, V, u);
                    __syncthreads();
                    srow[e] = (V >= vt) ? vtb : zb;
                    __syncthreads();
                    float acc2 = 0.f;
                    for (int d = 0; d < Dc; ++d)
                        acc2 = fmaf((float)srow[d], Wout[(size_t)d * Dc + e], acc2);
                    size_t r = (size_t)t * Bc + b;
                    float base = pd ? (float)dxR[r * Dc + e] : 0.f;
                    dxW[r * Dc + e] = (__bf16)(base + acc2);
                }
            }
        }
        __bf16* tmpw = dxW;
        dxW = (__bf16*)dxR;
        dxR = tmpw;
        __syncthreads();
    }
}

// ---------------------------------------------------------------------------
// Output PLIF scan fallback (gated; unchanged).
// ---------------------------------------------------------------------------
__global__ __launch_bounds__(256)
void out_scan2(const float* __restrict__ htok, const __bf16* __restrict__ dxf,
               const int* __restrict__ tok, const float* __restrict__ embed,
               const float* __restrict__ onw, const float* __restrict__ alpha_p,
               const float* __restrict__ obeta, const float* __restrict__ ovth,
               const int* __restrict__ flags, __bf16* __restrict__ decoded,
               const int* __restrict__ dirtyp)
{
    if (dirtyp[0] == 0) return;
    const int tid = threadIdx.x;
    const int s = blockIdx.x, b = blockIdx.y;
    const float al = alpha_p[0];
    const f32x4 bet = ((const f32x4*)obeta)[tid];
    const f32x4 vt  = ((const f32x4*)ovth)[tid];
    f32x4 a = bet, S = {1.f, 1.f, 1.f, 1.f};
#pragma unroll
    for (int i = 0; i < 5; ++i) {
#pragma unroll
        for (int c = 0; c < 4; ++c) { S[c] *= 1.0f + a[c]; a[c] *= a[c]; }
    }

    const int t0 = s * Kc;
    const int tlo = (t0 >= 64) ? t0 - 64 : 0;
    bool dirty = false;
    for (int c = tlo >> 6; c <= (t0 + Kc - 1) >> 6; ++c)
        dirty = dirty || gate_or(flags, NLc, c);

    f32x4 V = {0,0,0,0}, sum = {0,0,0,0};
    if (!dirty) {
        for (int tk = (s >= 2 ? s - 2 : 0); tk < s; ++tk) {
            f32x4 h = ((const f32x4*)(htok + ((size_t)tk * Bc + b) * Dc))[tid];
#pragma unroll
            for (int c = 0; c < 4; ++c) V[c] = fmaf(a[c], V[c], al * h[c] * S[c]);
        }
        f32x4 h = ((const f32x4*)(htok + ((size_t)s * Bc + b) * Dc))[tid];
        for (int k = 0; k < Kc; ++k) {
#pragma unroll
            for (int c = 0; c < 4; ++c) {
                V[c] = fmaf(bet[c], V[c], al * h[c]);
                sum[c] += (V[c] >= vt[c]) ? vt[c] : 0.f;
            }
        }
    } else {
        const f32x4 wv = ((const f32x4*)onw)[tid];
        __shared__ float red[4];
        for (int t = tlo; t < t0 + Kc; ++t) {
            const bool g = gate_or(flags, NLc, t >> 6);
            f32x4 h;
            if (g) {
                size_t r = (size_t)t * Bc + b;
                int id = tok[b * Sc + (t >> 5)];
                f32x4 v = ((const f32x4*)(embed + (size_t)id * Dc))[tid];
                bf16x4 dv = ((const bf16x4*)(dxf + r * Dc))[tid];
#pragma unroll
                for (int c = 0; c < 4; ++c) v[c] += (float)dv[c];
                float ss = v[0]*v[0] + v[1]*v[1] + v[2]*v[2] + v[3]*v[3];
#pragma unroll
                for (int off = 32; off >= 1; off >>= 1) ss += __shfl_down(ss, off);
                if ((tid & 63) == 0) red[tid >> 6] = ss;
                __syncthreads();
                float tot = red[0] + red[1] + red[2] + red[3];
                __syncthreads();
                float sc = rsqrtf(tot * (1.0f / Dc) + 1e-6f);
#pragma unroll
                for (int c = 0; c < 4; ++c) h[c] = v[c] * sc * wv[c];
            } else {
                h = ((const f32x4*)(htok + ((size_t)(t >> 5) * Bc + b) * Dc))[tid];
            }
#pragma unroll
            for (int c = 0; c < 4; ++c) {
                V[c] = fmaf(bet[c], V[c], al * h[c]);
                if (t >= t0) sum[c] += (V[c] >= vt[c]) ? vt[c] : 0.f;
            }
        }
    }
    bf16x4 o;
#pragma unroll
    for (int c = 0; c < 4; ++c) o[c] = (__bf16)(sum[c] * (1.0f / 32.0f));
    ((bf16x4*)(decoded + ((size_t)b * Sc + s) * Dc))[tid] = o;
}

// ---------------------------------------------------------------------------
// Fused prep (embed cast moved out):
//  [0,4096)     W_in -> wT_in (bf16 transpose, 32x32 tiles)
//  [4096,4608)  decode_w -> decw_bf (8 elems/thread)
//  [4608,5120)  token rows: xtok = bf16(emb[id]); h_tok = rmsnorm(emb[id])*onw
//               (r==0 also zeroes flags[0..512] incl. dirtyAny)
// ---------------------------------------------------------------------------
__global__ __launch_bounds__(256)
void prep(const float* __restrict__ W_in, const float* __restrict__ embed,
          const float* __restrict__ decode_w, const int* __restrict__ tok,
          const float* __restrict__ onw, __bf16* __restrict__ wT_in,
          __bf16* __restrict__ decw_bf,
          __bf16* __restrict__ xtok, float* __restrict__ h_tok,
          int* __restrict__ flags)
{
    const int blk = blockIdx.x;
    const int tid = threadIdx.x;
    if (blk < 4096) {
        __shared__ float tile[32][33];
        const int mat = blk >> 10;
        const int t2  = blk & 1023;
        const int d0  = (t2 & 31) * 32, e0 = (t2 >> 5) * 32;
        const float* Wm = W_in + (size_t)mat * Dc * Dc;
        __bf16*      Wo = wT_in + (size_t)mat * Dc * Dc;
        const int tx = tid & 31, ty = tid >> 5;
#pragma unroll
        for (int i = 0; i < 4; ++i)
            tile[ty + i*8][tx] = Wm[(size_t)(d0 + ty + i*8) * Dc + e0 + tx];
        __syncthreads();
        const int txp = tid & 15, tyw = tid >> 4;
#pragma unroll
        for (int i = 0; i < 2; ++i) {
            int r = tyw + 16 * i;
            bf16x2 o;
            o[0] = (__bf16)tile[2*txp][r];
            o[1] = (__bf16)tile[2*txp + 1][r];
            *(bf16x2*)(&Wo[(size_t)(e0 + r) * Dc + d0 + 2*txp]) = o;
        }
    } else if (blk < 4608) {                  // decode_w cast
        int idx = (blk - 4096) * 256 + tid;
        const f32x4* pp = (const f32x4*)decode_w + (size_t)idx * 2;
        f32x4 v0 = pp[0], v1 = pp[1];
        bf16x8 o;
        o[0]=(__bf16)v0[0]; o[1]=(__bf16)v0[1]; o[2]=(__bf16)v0[2]; o[3]=(__bf16)v0[3];
        o[4]=(__bf16)v1[0]; o[5]=(__bf16)v1[1]; o[6]=(__bf16)v1[2]; o[7]=(__bf16)v1[3];
        ((bf16x8*)decw_bf)[idx] = o;
    } else {
        const int r = blk - 4608;             // r = s*Bc + b
        if (r == 0) {
            flags[tid] = 0; flags[tid + 256] = 0;
            if (tid == 0) flags[512] = 0;     // dirtyAny
        }
        const int s = r >> 1, b = r & 1;
        const int id = tok[b * Sc + s];
        const f32x4 v = ((const f32x4*)(embed + (size_t)id * Dc))[tid];
        float ss = v[0]*v[0] + v[1]*v[1] + v[2]*v[2] + v[3]*v[3];
#pragma unroll
        for (int off = 32; off >= 1; off >>= 1) ss += __shfl_down(ss, off);
        __shared__ float red[4];
        if ((tid & 63) == 0) red[tid >> 6] = ss;
        __syncthreads();
        float tot = red[0] + red[1] + red[2] + red[3];
        float sc = rsqrtf(tot * (1.0f / Dc) + 1e-6f);
        const f32x4 wv = ((const f32x4*)onw)[tid];
        bf16x4 o; o[0]=(__bf16)v[0]; o[1]=(__bf16)v[1]; o[2]=(__bf16)v[2]; o[3]=(__bf16)v[3];
        ((bf16x4*)(xtok + (size_t)r * Dc))[tid] = o;
        f32x4 h = {v[0]*sc*wv[0], v[1]*sc*wv[1], v[2]*sc*wv[2], v[3]*sc*wv[3]};
        ((f32x4*)(h_tok + (size_t)r * Dc))[tid] = h;
    }
}

// RMSNorm over D=1024 per row -> bf16
__global__ __launch_bounds__(256)
void rmsnorm_rows(const float* __restrict__ in, const float* __restrict__ w,
                  __bf16* __restrict__ outb)
{
    const int r = blockIdx.x;
    const int tid = threadIdx.x;
    const f32x4 v = ((const f32x4*)(in + (size_t)r * Dc))[tid];
    float ss = v[0]*v[0] + v[1]*v[1] + v[2]*v[2] + v[3]*v[3];
#pragma unroll
    for (int off = 32; off >= 1; off >>= 1) ss += __shfl_down(ss, off);
    __shared__ float red[4];
    if ((tid & 63) == 0) red[tid >> 6] = ss;
    __syncthreads();
    float tot = red[0] + red[1] + red[2] + red[3];
    float sc = rsqrtf(tot * (1.0f / Dc) + 1e-6f);
    const f32x4 wv = ((const f32x4*)w)[tid];
    bf16x4 o;
    o[0]=(__bf16)(v[0]*sc*wv[0]); o[1]=(__bf16)(v[1]*sc*wv[1]);
    o[2]=(__bf16)(v[2]*sc*wv[2]); o[3]=(__bf16)(v[3]*sc*wv[3]);
    ((bf16x4*)(outb + (size_t)r * Dc))[tid] = o;
}

// ---------------------------------------------------------------------------
extern "C" void kernel_launch(void* const* d_in, const int* in_sizes, int n_in,
                              void* d_out, int out_size, void* d_ws, size_t ws_size,
                              hipStream_t stream)
{
    const int*   token_ids  = (const int*)  d_in[0];
    const float* embed      = (const float*)d_in[1];
    const float* W_in       = (const float*)d_in[2];
    const float* W_out      = (const float*)d_in[3];
    const float* layer_beta = (const float*)d_in[4];
    const float* layer_vth  = (const float*)d_in[5];
    const float* out_norm_w = (const float*)d_in[6];
    const float* out_beta   = (const float*)d_in[7];
    const float* out_vth    = (const float*)d_in[8];
    const float* out_alpha  = (const float*)d_in[9];
    const float* decode_w   = (const float*)d_in[10];
    const float* decode_b   = (const float*)d_in[11];
    const float* li_norm_w  = (const float*)d_in[12];
    float* out = (float*)d_out;

    size_t off = 0;
    auto alloc = [&](size_t bytes) -> void* {
        void* p = (char*)d_ws + off;
        off += (bytes + 255) & ~(size_t)255;
        return p;
    };
    __bf16* dxA      = (__bf16*)alloc((size_t)Tc * Bc * Dc * 2);   // ping-pong dx
    __bf16* dxB      = (__bf16*)alloc((size_t)Tc * Bc * Dc * 2);
    __bf16* u_tokall = (__bf16*)alloc((size_t)Bc * Sc * UTS * 2);  // [512][4096]
    float*  h_tok    = (float*) alloc((size_t)Bc * Sc * Dc * 4);
    __bf16* xtok     = (__bf16*)alloc((size_t)Bc * Sc * Dc * 2);
    __bf16* wT_in    = (__bf16*)alloc((size_t)NLc * Dc * Dc * 2);
    __bf16* emb_bf   = (__bf16*)alloc((size_t)Vc * Dc * 2);
    __bf16* decw_bf  = (__bf16*)alloc((size_t)Dc * Dc * 2);
    __bf16* decoded  = (__bf16*)alloc((size_t)Bc * Sc * Dc * 2);
    float*  h2       = (float*) alloc((size_t)Bc * Sc * Dc * 4);
    __bf16* h2n      = (__bf16*)alloc((size_t)Bc * Sc * Dc * 2);
    int*    flags    = (int*)   alloc(((size_t)NLc * NPANEL + 64) * 4);
    int*    dirtyAny = flags + NLc * NPANEL;   // flags[512]

    // 1. fused prep (W_in transpose+cast, decw cast, token rows, flags)
    prep<<<5120, 256, 0, stream>>>(W_in, embed, decode_w, token_ids, out_norm_w,
                                   wT_in, decw_bf, xtok, h_tok, flags);

    // 2. u-GEMM (512 blocks) co-tenant with embed->bf16 cast (3072 blocks)
    gemm_u_cast<<<512 + Vc * Dc / 8 / 256, 256, 0, stream>>>(
        xtok, wT_in, u_tokall, embed, emb_bf);

    // 3a. speculative whole-network scan (flags + decoded, clean assumption)
    spec_scan<<<NPANEL, 1024, 0, stream>>>(
        u_tokall, layer_beta, layer_vth, h_tok, out_alpha, out_beta, out_vth,
        decoded, flags, dirtyAny);

    // 3b. gated fallback (single-block all-layers) + gated out rewrite
    fallback_layers<<<1, 1024, 0, stream>>>(
        u_tokall, W_in, W_out, layer_beta, layer_vth, dxA, dxB, flags, dirtyAny);
    out_scan2<<<dim3(Sc, Bc), 256, 0, stream>>>(
        h_tok, dxA, token_ids, embed, out_norm_w, out_alpha, out_beta, out_vth,
        flags, decoded, dirtyAny);   // dx after even #layers ends in dxA

    // 4. decode head (32x64, BK=256 -> 256 blocks)
    gemm_bt<2, 32, 64, 256><<<dim3(Dc / 64, (Bc * Sc) / 32), 256, 0, stream>>>(
        decoded, decw_bf, Bc * Sc, Dc, Dc, h2, nullptr, decode_b);
    rmsnorm_rows<<<Bc * Sc, 256, 0, stream>>>(h2, li_norm_w, h2n);
    // LM head 64x64, BK=128 -> 768 blocks (3/CU)
    gemm_bt<0, 64, 64, 128><<<dim3(Vc / 64, (Bc * Sc) / 64), 256, 0, stream>>>(
        h2n, emb_bf, Bc * Sc, Vc, Dc, out, nullptr, nullptr);
}

// Round 18
// 70.085 us; speedup vs baseline: 1.0020x; 1.0020x over previous
//
#include <hip/hip_runtime.h>

typedef __bf16 bf16x8 __attribute__((ext_vector_type(8)));
typedef __bf16 bf16x4 __attribute__((ext_vector_type(4)));
typedef __bf16 bf16x2 __attribute__((ext_vector_type(2)));
typedef float  f32x4  __attribute__((ext_vector_type(4)));
typedef float  f32x16 __attribute__((ext_vector_type(16)));

constexpr int Bc = 2, Sc = 256, Kc = 32, Tc = 8192, Dc = 1024, Vc = 6144, NLc = 4;
constexpr int NPANEL = (Tc * Bc) / 128;   // 128 chunks (64 frames x both batches)
constexpr int UTS = NLc * Dc;             // u_tok_all row stride (4096)

__device__ __forceinline__ void gload16(const void* g, void* l) {
    __builtin_amdgcn_global_load_lds(
        (const __attribute__((address_space(1))) unsigned int*)g,
        (__attribute__((address_space(3))) unsigned int*)l,
        16, 0, 0);
}

// bijective XCD-aware block swizzle (m204 variant)
__device__ __forceinline__ int xcd_swz(int lin, int nwg) {
    int q = nwg >> 3, r = nwg & 7;
    int x = lin & 7, o = lin >> 3;
    int base = (x < r) ? x * (q + 1) : r * (q + 1) + (x - r) * q;
    return base + o;
}

// OR of n flag arrays (stride NPANEL) at chunk p
__device__ __forceinline__ bool gate_or(const int* f, int n, int p) {
    bool g = false;
    for (int j = 0; j < n; ++j) g = g || (f[j * NPANEL + p] != 0);
    return g;
}

// ---------------------------------------------------------------------------
// GEMM (16x16x32 path, kept for the small decode GEMM): C = A x BT.
// EPI 2: Cout=acc+bias[col]
// ---------------------------------------------------------------------------
template<int EPI, int BM, int BN, int BK>
__global__ __launch_bounds__(256)
void gemm_bt(const __bf16* __restrict__ A, const __bf16* __restrict__ BT,
             int M, int N, int Kd,
             float* __restrict__ Cout, __bf16* __restrict__ outb,
             const float* __restrict__ bias)
{
    constexpr int MI = BM / 32, NI = BN / 32;
    constexpr int KCH  = BK / 8;
    constexpr int SWM  = KCH - 1;
    constexpr int ROWB = BK * 2;
    constexpr int CA = BM * KCH / 256;
    constexpr int CB = BN * KCH / 256;
    __shared__ char lds[(BM + BN) * ROWB];
    char* As = lds;
    char* Bs = lds + BM * ROWB;
    const int tid  = threadIdx.x;
    const int lane = tid & 63;
    const int wid  = tid >> 6;
    const int wm   = wid & 1, wn = wid >> 1;

    const int nwg = gridDim.x * gridDim.y;
    const int lin = blockIdx.y * gridDim.x + blockIdx.x;
    const int swz = xcd_swz(lin, nwg);
    const int bn  = (swz % gridDim.x) * BN;
    const int bm  = (swz / gridDim.x) * BM;

    const __bf16* asrc[CA];
#pragma unroll
    for (int i = 0; i < CA; ++i) {
        int chunk = i * 256 + tid;
        int row = chunk / KCH, kc = chunk % KCH;
        int kcs = kc ^ (row & SWM);
        asrc[i] = A + (size_t)(bm + row) * Kd + kcs * 8;
    }
    const __bf16* bsrc[CB];
#pragma unroll
    for (int i = 0; i < CB; ++i) {
        int chunk = i * 256 + tid;
        int row = chunk / KCH, kc = chunk % KCH;
        int kcs = kc ^ (row & SWM);
        bsrc[i] = BT + (size_t)(bn + row) * Kd + kcs * 8;
    }

    f32x4 acc[MI][NI] = {};

    for (int kt = 0; kt < Kd; kt += BK) {
#pragma unroll
        for (int i = 0; i < CA; ++i)
            gload16(asrc[i] + kt, As + (i * 256 + tid) * 16);
#pragma unroll
        for (int i = 0; i < CB; ++i)
            gload16(bsrc[i] + kt, Bs + (i * 256 + tid) * 16);
        __syncthreads();
#pragma unroll
        for (int kk = 0; kk < BK / 32; ++kk) {
            const int ko = kk * 64 + ((lane >> 4) << 4);
            bf16x8 af[MI], bfr[NI];
#pragma unroll
            for (int mi = 0; mi < MI; ++mi) {
                int row = wm * (BM / 2) + mi * 16 + (lane & 15);
                af[mi] = *(const bf16x8*)(As + row * ROWB +
                                          (ko ^ ((row & SWM) << 4)));
            }
#pragma unroll
            for (int ni = 0; ni < NI; ++ni) {
                int row = wn * (BN / 2) + ni * 16 + (lane & 15);
                bfr[ni] = *(const bf16x8*)(Bs + row * ROWB +
                                           (ko ^ ((row & SWM) << 4)));
            }
#pragma unroll
            for (int mi = 0; mi < MI; ++mi)
#pragma unroll
                for (int ni = 0; ni < NI; ++ni)
                    acc[mi][ni] = __builtin_amdgcn_mfma_f32_16x16x32_bf16(
                        af[mi], bfr[ni], acc[mi][ni], 0, 0, 0);
        }
        __syncthreads();
    }

    const int cc = lane & 15, cr = (lane >> 4) * 4;
#pragma unroll
    for (int mi = 0; mi < MI; ++mi) {
#pragma unroll
        for (int ni = 0; ni < NI; ++ni) {
            int gcol = bn + wn * (BN / 2) + ni * 16 + cc;
#pragma unroll
            for (int r = 0; r < 4; ++r) {
                int grow = bm + wm * (BM / 2) + mi * 16 + cr + r;
                size_t idx = (size_t)grow * N + gcol;
                float v = acc[mi][ni][r];
                if (EPI == 0)      Cout[idx] = v;
                else if (EPI == 2) Cout[idx] = v + bias[gcol];
                else               outb[idx] = (__bf16)v;
            }
        }
    }
}

// ---------------------------------------------------------------------------
// GEMM via 32x32x16 MFMA (hot path): 64x64 block, 4 waves (2x2), each wave
// ONE 32x32 tile (f32x16 acc). +18% matrix-pipe efficiency vs 16x16 (m119)
// and half the MFMA instruction count. A/B frag: row=lane&31, k=8*(l>>5)+j.
// C/D: col=lane&31, row=(reg&3)+8*(reg>>2)+4*(lane>>5)  [m74/m101].
// EPI 0: Cout=acc   EPI 3: outb=bf16(acc)
// ---------------------------------------------------------------------------
template<int EPI, int BK>
__global__ __launch_bounds__(256)
void gemm32(const __bf16* __restrict__ A, const __bf16* __restrict__ BT,
            int M, int N, int Kd,
            float* __restrict__ Cout, __bf16* __restrict__ outb)
{
    constexpr int BM = 64, BN = 64;
    constexpr int KCH  = BK / 8;
    constexpr int SWM  = KCH - 1;
    constexpr int ROWB = BK * 2;
    constexpr int CA = BM * KCH / 256;
    constexpr int CB = BN * KCH / 256;
    __shared__ char lds[(BM + BN) * ROWB];
    char* As = lds;
    char* Bs = lds + BM * ROWB;
    const int tid  = threadIdx.x;
    const int lane = tid & 63;
    const int wid  = tid >> 6;
    const int wm   = wid & 1, wn = wid >> 1;

    const int nwg = gridDim.x * gridDim.y;
    const int lin = blockIdx.y * gridDim.x + blockIdx.x;
    const int swz = xcd_swz(lin, nwg);
    const int bn  = (swz % gridDim.x) * BN;
    const int bm  = (swz / gridDim.x) * BM;

    const __bf16* asrc[CA];
#pragma unroll
    for (int i = 0; i < CA; ++i) {
        int chunk = i * 256 + tid;
        int row = chunk / KCH, kc = chunk % KCH;
        int kcs = kc ^ (row & SWM);
        asrc[i] = A + (size_t)(bm + row) * Kd + kcs * 8;
    }
    const __bf16* bsrc[CB];
#pragma unroll
    for (int i = 0; i < CB; ++i) {
        int chunk = i * 256 + tid;
        int row = chunk / KCH, kc = chunk % KCH;
        int kcs = kc ^ (row & SWM);
        bsrc[i] = BT + (size_t)(bn + row) * Kd + kcs * 8;
    }

    f32x16 acc = {};
    const int arow = wm * 32 + (lane & 31);
    const int brow = wn * 32 + (lane & 31);
    const int kg   = (lane >> 5) << 4;        // k-group byte offset

    for (int kt = 0; kt < Kd; kt += BK) {
#pragma unroll
        for (int i = 0; i < CA; ++i)
            gload16(asrc[i] + kt, As + (i * 256 + tid) * 16);
#pragma unroll
        for (int i = 0; i < CB; ++i)
            gload16(bsrc[i] + kt, Bs + (i * 256 + tid) * 16);
        __syncthreads();
#pragma unroll
        for (int kk = 0; kk < BK / 16; ++kk) {
            const int ko = kk * 32 + kg;
            bf16x8 af = *(const bf16x8*)(As + arow * ROWB +
                                         (ko ^ ((arow & SWM) << 4)));
            bf16x8 bfr = *(const bf16x8*)(Bs + brow * ROWB +
                                          (ko ^ ((brow & SWM) << 4)));
            acc = __builtin_amdgcn_mfma_f32_32x32x16_bf16(af, bfr, acc, 0, 0, 0);
        }
        __syncthreads();
    }

    const int gcol = bn + wn * 32 + (lane & 31);
    const int rbase = bm + wm * 32 + 4 * (lane >> 5);
#pragma unroll
    for (int r = 0; r < 16; ++r) {
        int grow = rbase + (r & 3) + 8 * (r >> 2);
        size_t idx = (size_t)grow * N + gcol;
        if (EPI == 0) Cout[idx] = acc[r];
        else          outb[idx] = (__bf16)acc[r];
    }
}

// ---------------------------------------------------------------------------
// Hybrid: u-GEMM (512 blocks, 64x64 via 32x32 MFMA, BK=256) co-tenant with
// the embed->bf16 cast (3072 streaming blocks). emb_bf consumed only by the
// LM head, 4 kernel boundaries later — no race.
// ---------------------------------------------------------------------------
__global__ __launch_bounds__(256)
void gemm_u_cast(const __bf16* __restrict__ A, const __bf16* __restrict__ BT,
                 __bf16* __restrict__ outb,
                 const float* __restrict__ embed, __bf16* __restrict__ emb_bf)
{
    constexpr int BM = 64, BN = 64, BK = 256;
    constexpr int GX = UTS / BN;          // 64 N-tiles
    constexpr int NGEMM = GX * (Bc * Sc / BM);   // 512
    constexpr int KCH  = BK / 8, SWM = KCH - 1, ROWB = BK * 2;
    constexpr int CA = BM * KCH / 256, CB = BN * KCH / 256;
    const int tid = threadIdx.x;

    if (blockIdx.x >= NGEMM) {            // ---- cast role
        int idx = (blockIdx.x - NGEMM) * 256 + tid;
        const f32x4* pp = (const f32x4*)embed + (size_t)idx * 2;
        f32x4 v0 = pp[0], v1 = pp[1];
        bf16x8 o;
        o[0]=(__bf16)v0[0]; o[1]=(__bf16)v0[1]; o[2]=(__bf16)v0[2]; o[3]=(__bf16)v0[3];
        o[4]=(__bf16)v1[0]; o[5]=(__bf16)v1[1]; o[6]=(__bf16)v1[2]; o[7]=(__bf16)v1[3];
        ((bf16x8*)emb_bf)[idx] = o;
        return;
    }

    // ---- GEMM role (32x32 MFMA, EPI=3)
    __shared__ char lds[(BM + BN) * ROWB];
    char* As = lds;
    char* Bs = lds + BM * ROWB;
    const int lane = tid & 63;
    const int wid  = tid >> 6;
    const int wm   = wid & 1, wn = wid >> 1;
    const int swz = xcd_swz(blockIdx.x, NGEMM);
    const int bn  = (swz % GX) * BN;
    const int bm  = (swz / GX) * BM;
    const int Kd  = Dc, N = UTS;

    const __bf16* asrc[CA];
#pragma unroll
    for (int i = 0; i < CA; ++i) {
        int chunk = i * 256 + tid;
        int row = chunk / KCH, kc = chunk % KCH;
        int kcs = kc ^ (row & SWM);
        asrc[i] = A + (size_t)(bm + row) * Kd + kcs * 8;
    }
    const __bf16* bsrc[CB];
#pragma unroll
    for (int i = 0; i < CB; ++i) {
        int chunk = i * 256 + tid;
        int row = chunk / KCH, kc = chunk % KCH;
        int kcs = kc ^ (row & SWM);
        bsrc[i] = BT + (size_t)(bn + row) * Kd + kcs * 8;
    }

    f32x16 acc = {};
    const int arow = wm * 32 + (lane & 31);
    const int brow = wn * 32 + (lane & 31);
    const int kg   = (lane >> 5) << 4;

    for (int kt = 0; kt < Kd; kt += BK) {
#pragma unroll
        for (int i = 0; i < CA; ++i)
            gload16(asrc[i] + kt, As + (i * 256 + tid) * 16);
#pragma unroll
        for (int i = 0; i < CB; ++i)
            gload16(bsrc[i] + kt, Bs + (i * 256 + tid) * 16);
        __syncthreads();
#pragma unroll
        for (int kk = 0; kk < BK / 16; ++kk) {
            const int ko = kk * 32 + kg;
            bf16x8 af = *(const bf16x8*)(As + arow * ROWB +
                                         (ko ^ ((arow & SWM) << 4)));
            bf16x8 bfr = *(const bf16x8*)(Bs + brow * ROWB +
                                          (ko ^ ((brow & SWM) << 4)));
            acc = __builtin_amdgcn_mfma_f32_32x32x16_bf16(af, bfr, acc, 0, 0, 0);
        }
        __syncthreads();
    }

    const int gcol = bn + wn * 32 + (lane & 31);
    const int rbase = bm + wm * 32 + 4 * (lane >> 5);
#pragma unroll
    for (int r = 0; r < 16; ++r) {
        int grow = rbase + (r & 3) + 8 * (r >> 2);
        outb[(size_t)grow * N + gcol] = (__bf16)acc[r];
    }
}

// ---------------------------------------------------------------------------
// Speculative whole-network scan (unchanged, proven r13-r17).
// ---------------------------------------------------------------------------
__global__ __launch_bounds__(1024)
void spec_scan(const __bf16* __restrict__ utok_base,
               const float* __restrict__ lbeta, const float* __restrict__ lvth,
               const float* __restrict__ htok, const float* __restrict__ alpha_p,
               const float* __restrict__ obeta, const float* __restrict__ ovth,
               __bf16* __restrict__ decoded, int* __restrict__ flags,
               int* __restrict__ dirtyAny)
{
    const int e = threadIdx.x;
    const int p = blockIdx.x;
    __shared__ int fm;
    if (e == 0) fm = 0;
    __syncthreads();

    unsigned mybits = 0;
#pragma unroll
    for (int l = 0; l < NLc; ++l) {
        const __bf16* utok = utok_base + (size_t)l * Dc;
        const float bet = lbeta[l * Dc + e], vt = lvth[l * Dc + e];
        float a = bet, S = 1.0f;
#pragma unroll
        for (int i = 0; i < 5; ++i) { S = S * (1.0f + a); a = a * a; }
        bool spike = false;
        for (int b = 0; b < Bc; ++b) {
            float V = 0.f;
            if (p > 0) {
#pragma unroll
                for (int ti = 0; ti < 2; ++ti) {
                    float u = (float)utok[((size_t)(2 * p - 2 + ti) * Bc + b) * UTS + e];
                    V = fmaf(a, V, u * S);
                }
            }
#pragma unroll
            for (int ti = 0; ti < 2; ++ti) {
                float u = (float)utok[((size_t)(2 * p + ti) * Bc + b) * UTS + e];
                float V1 = fmaf(bet, V, u);
                V = fmaf(a, V, u * S);
                spike = spike || (fmaxf(V1, V) >= vt);
            }
        }
        if (spike) mybits |= 1u << l;
    }
    unsigned wor = 0;
#pragma unroll
    for (int l = 0; l < NLc; ++l)
        if (__any(mybits & (1u << l))) wor |= 1u << l;
    if ((e & 63) == 0 && wor) atomicOr(&fm, (int)wor);
    __syncthreads();
    const int f = fm;
    if (e < NLc) flags[e * NPANEL + p] = (f >> e) & 1;
    if (e == 0 && f) atomicOr(dirtyAny, 1);

    const int w = e >> 6, lane = e & 63;
    const int ridx = w & 3, cq = w >> 2;
    const int s = 2 * p + (ridx >> 1), b = ridx & 1;
    const int gi = lane + 64 * cq;
    const float al = alpha_p[0];
    const f32x4 obet = ((const f32x4*)obeta)[gi];
    const f32x4 ovt  = ((const f32x4*)ovth)[gi];
    f32x4 oa = obet, oS = {1.f, 1.f, 1.f, 1.f};
#pragma unroll
    for (int i = 0; i < 5; ++i) {
#pragma unroll
        for (int c = 0; c < 4; ++c) { oS[c] *= 1.0f + oa[c]; oa[c] *= oa[c]; }
    }
    f32x4 V = {0, 0, 0, 0}, sum = {0, 0, 0, 0};
    for (int tk = (s >= 2 ? s - 2 : 0); tk < s; ++tk) {
        f32x4 h = ((const f32x4*)(htok + ((size_t)tk * Bc + b) * Dc))[gi];
#pragma unroll
        for (int c = 0; c < 4; ++c) V[c] = fmaf(oa[c], V[c], al * h[c] * oS[c]);
    }
    f32x4 h = ((const f32x4*)(htok + ((size_t)s * Bc + b) * Dc))[gi];
    for (int k = 0; k < Kc; ++k) {
#pragma unroll
        for (int c = 0; c < 4; ++c) {
            V[c] = fmaf(obet[c], V[c], al * h[c]);
            sum[c] += (V[c] >= ovt[c]) ? ovt[c] : 0.f;
        }
    }
    bf16x4 o;
#pragma unroll
    for (int c = 0; c < 4; ++c) o[c] = (__bf16)(sum[c] * (1.0f / 32.0f));
    ((bf16x4*)(decoded + ((size_t)b * Sc + s) * Dc))[gi] = o;
}

// ---------------------------------------------------------------------------
// Single-block gated fallback (unchanged, proven).
// ---------------------------------------------------------------------------
__global__ __launch_bounds__(1024)
void fallback_layers(const __bf16* __restrict__ utok_base,
                     const float* __restrict__ W_in, const float* __restrict__ W_out,
                     const float* __restrict__ lbeta, const float* __restrict__ lvth,
                     __bf16* __restrict__ dxA, __bf16* __restrict__ dxB,
                     int* __restrict__ flags_all, const int* __restrict__ dirty)
{
    if (dirty[0] == 0) return;
    const int e = threadIdx.x;
    __shared__ int fm;
    __shared__ __bf16 srow[Dc];
    const __bf16* dxR = dxA;
    __bf16*       dxW = dxB;

    for (int l = 0; l < NLc; ++l) {
        const __bf16* utok = utok_base + (size_t)l * Dc;
        const float*  Win  = W_in  + (size_t)l * Dc * Dc;
        const float*  Wout = W_out + (size_t)l * Dc * Dc;
        const float bet = lbeta[l * Dc + e], vt = lvth[l * Dc + e];
        float a = bet, S = 1.0f;
#pragma unroll
        for (int i = 0; i < 5; ++i) { S = S * (1.0f + a); a = a * a; }
        int* flags_l = flags_all + l * NPANEL;
        const __bf16 vtb = (__bf16)vt, zb = (__bf16)0.f;

        for (int p = 0; p < NPANEL; ++p) {
            const int t0 = p * 64;
            __syncthreads();
            if (e == 0) fm = 0;
            __syncthreads();
            const bool pd  = gate_or(flags_all, l, p);
            const bool pdw = (p > 0) && gate_or(flags_all, l, p - 1);

            auto ut = [&](int tk, int b) -> float {
                return (float)utok[((size_t)tk * Bc + b) * UTS + e];
            };
            auto du_at = [&](int t, int b) -> float {
                __syncthreads();
                srow[e] = dxR[((size_t)t * Bc + b) * Dc + e];
                __syncthreads();
                float acc = 0.f;
                for (int d = 0; d < Dc; ++d)
                    acc = fmaf((float)srow[d], Win[(size_t)d * Dc + e], acc);
                return acc;
            };

            bool spike = false;
            for (int b = 0; b < Bc; ++b) {
                float V = 0.f;
                if (p > 0) {
                    if (!pdw) {
                        for (int ti = 0; ti < 2; ++ti)
                            V = fmaf(a, V, ut(2 * p - 2 + ti, b) * S);
                    } else {
                        for (int t = t0 - 64; t < t0; ++t)
                            V = fmaf(bet, V, ut(t >> 5, b) + du_at(t, b));
                    }
                }
                if (!pd) {
                    for (int ti = 0; ti < 2; ++ti) {
                        const float u = ut(2 * p + ti, b);
                        float V1 = fmaf(bet, V, u);
                        V = fmaf(a, V, u * S);
                        spike = spike || (fmaxf(V1, V) >= vt);
                    }
                } else {
                    for (int k = 0; k < 64; ++k) {
                        V = fmaf(bet, V, ut((t0 + k) >> 5, b) + du_at(t0 + k, b));
                        spike = spike || (V >= vt);
                    }
                }
            }
            if (__any(spike) && (e & 63) == 0) atomicOr(&fm, 1);
            __syncthreads();
            const bool f = (fm != 0);
            if (e == 0) flags_l[p] = f ? 1 : 0;
            __syncthreads();

            if (!f) {
                if (pd) {
                    for (int rr = 0; rr < 128; ++rr)
                        dxW[(size_t)(t0 * Bc + rr) * Dc + e] =
                            dxR[(size_t)(t0 * Bc + rr) * Dc + e];
                }
                continue;
            }
            for (int b = 0; b < Bc; ++b) {
                float V = 0.f;
                if (p > 0) {
                    if (!pdw) {
                        for (int ti = 0; ti < 2; ++ti)
                            V = fmaf(a, V, ut(2 * p - 2 + ti, b) * S);
                    } else {
                        for (int t = t0 - 64; t < t0; ++t)
                            V = fmaf(bet, V, ut(t >> 5, b) + du_at(t, b));
                    }
                }
                for (int k = 0; k < 64; ++k) {
                    const int t = t0 + k;
                    float u = ut(t >> 5, b);
                    if (pd) u += du_at(t, b);
                    V = fmaf(bet, V, u);
                    __syncthreads();
                    srow[e] = (V >= vt) ? vtb : zb;
                    __syncthreads();
                    float acc2 = 0.f;
                    for (int d = 0; d < Dc; ++d)
                        acc2 = fmaf((float)srow[d], Wout[(size_t)d * Dc + e], acc2);
                    size_t r = (size_t)t * Bc + b;
                    float base = pd ? (float)dxR[r * Dc + e] : 0.f;
                    dxW[r * Dc + e] = (__bf16)(base + acc2);
                }
            }
        }
        __bf16* tmpw = dxW;
        dxW = (__bf16*)dxR;
        dxR = tmpw;
        __syncthreads();
    }
}

// ---------------------------------------------------------------------------
// Output PLIF scan fallback (gated; unchanged).
// ---------------------------------------------------------------------------
__global__ __launch_bounds__(256)
void out_scan2(const float* __restrict__ htok, const __bf16* __restrict__ dxf,
               const int* __restrict__ tok, const float* __restrict__ embed,
               const float* __restrict__ onw, const float* __restrict__ alpha_p,
               const float* __restrict__ obeta, const float* __restrict__ ovth,
               const int* __restrict__ flags, __bf16* __restrict__ decoded,
               const int* __restrict__ dirtyp)
{
    if (dirtyp[0] == 0) return;
    const int tid = threadIdx.x;
    const int s = blockIdx.x, b = blockIdx.y;
    const float al = alpha_p[0];
    const f32x4 bet = ((const f32x4*)obeta)[tid];
    const f32x4 vt  = ((const f32x4*)ovth)[tid];
    f32x4 a = bet, S = {1.f, 1.f, 1.f, 1.f};
#pragma unroll
    for (int i = 0; i < 5; ++i) {
#pragma unroll
        for (int c = 0; c < 4; ++c) { S[c] *= 1.0f + a[c]; a[c] *= a[c]; }
    }

    const int t0 = s * Kc;
    const int tlo = (t0 >= 64) ? t0 - 64 : 0;
    bool dirty = false;
    for (int c = tlo >> 6; c <= (t0 + Kc - 1) >> 6; ++c)
        dirty = dirty || gate_or(flags, NLc, c);

    f32x4 V = {0,0,0,0}, sum = {0,0,0,0};
    if (!dirty) {
        for (int tk = (s >= 2 ? s - 2 : 0); tk < s; ++tk) {
            f32x4 h = ((const f32x4*)(htok + ((size_t)tk * Bc + b) * Dc))[tid];
#pragma unroll
            for (int c = 0; c < 4; ++c) V[c] = fmaf(a[c], V[c], al * h[c] * S[c]);
        }
        f32x4 h = ((const f32x4*)(htok + ((size_t)s * Bc + b) * Dc))[tid];
        for (int k = 0; k < Kc; ++k) {
#pragma unroll
            for (int c = 0; c < 4; ++c) {
                V[c] = fmaf(bet[c], V[c], al * h[c]);
                sum[c] += (V[c] >= vt[c]) ? vt[c] : 0.f;
            }
        }
    } else {
        const f32x4 wv = ((const f32x4*)onw)[tid];
        __shared__ float red[4];
        for (int t = tlo; t < t0 + Kc; ++t) {
            const bool g = gate_or(flags, NLc, t >> 6);
            f32x4 h;
            if (g) {
                size_t r = (size_t)t * Bc + b;
                int id = tok[b * Sc + (t >> 5)];
                f32x4 v = ((const f32x4*)(embed + (size_t)id * Dc))[tid];
                bf16x4 dv = ((const bf16x4*)(dxf + r * Dc))[tid];
#pragma unroll
                for (int c = 0; c < 4; ++c) v[c] += (float)dv[c];
                float ss = v[0]*v[0] + v[1]*v[1] + v[2]*v[2] + v[3]*v[3];
#pragma unroll
                for (int off = 32; off >= 1; off >>= 1) ss += __shfl_down(ss, off);
                if ((tid & 63) == 0) red[tid >> 6] = ss;
                __syncthreads();
                float tot = red[0] + red[1] + red[2] + red[3];
                __syncthreads();
                float sc = rsqrtf(tot * (1.0f / Dc) + 1e-6f);
#pragma unroll
                for (int c = 0; c < 4; ++c) h[c] = v[c] * sc * wv[c];
            } else {
                h = ((const f32x4*)(htok + ((size_t)(t >> 5) * Bc + b) * Dc))[tid];
            }
#pragma unroll
            for (int c = 0; c < 4; ++c) {
                V[c] = fmaf(bet[c], V[c], al * h[c]);
                if (t >= t0) sum[c] += (V[c] >= vt[c]) ? vt[c] : 0.f;
            }
        }
    }
    bf16x4 o;
#pragma unroll
    for (int c = 0; c < 4; ++c) o[c] = (__bf16)(sum[c] * (1.0f / 32.0f));
    ((bf16x4*)(decoded + ((size_t)b * Sc + s) * Dc))[tid] = o;
}

// ---------------------------------------------------------------------------
// Fused prep (embed cast lives in gemm_u_cast):
//  [0,4096)     W_in -> wT_in (bf16 transpose, 32x32 tiles)
//  [4096,4608)  decode_w -> decw_bf (8 elems/thread)
//  [4608,5120)  token rows: xtok = bf16(emb[id]); h_tok = rmsnorm(emb[id])*onw
//               (r==0 also zeroes flags[0..512] incl. dirtyAny)
// ---------------------------------------------------------------------------
__global__ __launch_bounds__(256)
void prep(const float* __restrict__ W_in, const float* __restrict__ embed,
          const float* __restrict__ decode_w, const int* __restrict__ tok,
          const float* __restrict__ onw, __bf16* __restrict__ wT_in,
          __bf16* __restrict__ decw_bf,
          __bf16* __restrict__ xtok, float* __restrict__ h_tok,
          int* __restrict__ flags)
{
    const int blk = blockIdx.x;
    const int tid = threadIdx.x;
    if (blk < 4096) {
        __shared__ float tile[32][33];
        const int mat = blk >> 10;
        const int t2  = blk & 1023;
        const int d0  = (t2 & 31) * 32, e0 = (t2 >> 5) * 32;
        const float* Wm = W_in + (size_t)mat * Dc * Dc;
        __bf16*      Wo = wT_in + (size_t)mat * Dc * Dc;
        const int tx = tid & 31, ty = tid >> 5;
#pragma unroll
        for (int i = 0; i < 4; ++i)
            tile[ty + i*8][tx] = Wm[(size_t)(d0 + ty + i*8) * Dc + e0 + tx];
        __syncthreads();
        const int txp = tid & 15, tyw = tid >> 4;
#pragma unroll
        for (int i = 0; i < 2; ++i) {
            int r = tyw + 16 * i;
            bf16x2 o;
            o[0] = (__bf16)tile[2*txp][r];
            o[1] = (__bf16)tile[2*txp + 1][r];
            *(bf16x2*)(&Wo[(size_t)(e0 + r) * Dc + d0 + 2*txp]) = o;
        }
    } else if (blk < 4608) {                  // decode_w cast
        int idx = (blk - 4096) * 256 + tid;
        const f32x4* pp = (const f32x4*)decode_w + (size_t)idx * 2;
        f32x4 v0 = pp[0], v1 = pp[1];
        bf16x8 o;
        o[0]=(__bf16)v0[0]; o[1]=(__bf16)v0[1]; o[2]=(__bf16)v0[2]; o[3]=(__bf16)v0[3];
        o[4]=(__bf16)v1[0]; o[5]=(__bf16)v1[1]; o[6]=(__bf16)v1[2]; o[7]=(__bf16)v1[3];
        ((bf16x8*)decw_bf)[idx] = o;
    } else {
        const int r = blk - 4608;             // r = s*Bc + b
        if (r == 0) {
            flags[tid] = 0; flags[tid + 256] = 0;
            if (tid == 0) flags[512] = 0;     // dirtyAny
        }
        const int s = r >> 1, b = r & 1;
        const int id = tok[b * Sc + s];
        const f32x4 v = ((const f32x4*)(embed + (size_t)id * Dc))[tid];
        float ss = v[0]*v[0] + v[1]*v[1] + v[2]*v[2] + v[3]*v[3];
#pragma unroll
        for (int off = 32; off >= 1; off >>= 1) ss += __shfl_down(ss, off);
        __shared__ float red[4];
        if ((tid & 63) == 0) red[tid >> 6] = ss;
        __syncthreads();
        float tot = red[0] + red[1] + red[2] + red[3];
        float sc = rsqrtf(tot * (1.0f / Dc) + 1e-6f);
        const f32x4 wv = ((const f32x4*)onw)[tid];
        bf16x4 o; o[0]=(__bf16)v[0]; o[1]=(__bf16)v[1]; o[2]=(__bf16)v[2]; o[3]=(__bf16)v[3];
        ((bf16x4*)(xtok + (size_t)r * Dc))[tid] = o;
        f32x4 h = {v[0]*sc*wv[0], v[1]*sc*wv[1], v[2]*sc*wv[2], v[3]*sc*wv[3]};
        ((f32x4*)(h_tok + (size_t)r * Dc))[tid] = h;
    }
}

// RMSNorm over D=1024 per row -> bf16
__global__ __launch_bounds__(256)
void rmsnorm_rows(const float* __restrict__ in, const float* __restrict__ w,
                  __bf16* __restrict__ outb)
{
    const int r = blockIdx.x;
    const int tid = threadIdx.x;
    const f32x4 v = ((const f32x4*)(in + (size_t)r * Dc))[tid];
    float ss = v[0]*v[0] + v[1]*v[1] + v[2]*v[2] + v[3]*v[3];
#pragma unroll
    for (int off = 32; off >= 1; off >>= 1) ss += __shfl_down(ss, off);
    __shared__ float red[4];
    if ((tid & 63) == 0) red[tid >> 6] = ss;
    __syncthreads();
    float tot = red[0] + red[1] + red[2] + red[3];
    float sc = rsqrtf(tot * (1.0f / Dc) + 1e-6f);
    const f32x4 wv = ((const f32x4*)w)[tid];
    bf16x4 o;
    o[0]=(__bf16)(v[0]*sc*wv[0]); o[1]=(__bf16)(v[1]*sc*wv[1]);
    o[2]=(__bf16)(v[2]*sc*wv[2]); o[3]=(__bf16)(v[3]*sc*wv[3]);
    ((bf16x4*)(outb + (size_t)r * Dc))[tid] = o;
}

// ---------------------------------------------------------------------------
extern "C" void kernel_launch(void* const* d_in, const int* in_sizes, int n_in,
                              void* d_out, int out_size, void* d_ws, size_t ws_size,
                              hipStream_t stream)
{
    const int*   token_ids  = (const int*)  d_in[0];
    const float* embed      = (const float*)d_in[1];
    const float* W_in       = (const float*)d_in[2];
    const float* W_out      = (const float*)d_in[3];
    const float* layer_beta = (const float*)d_in[4];
    const float* layer_vth  = (const float*)d_in[5];
    const float* out_norm_w = (const float*)d_in[6];
    const float* out_beta   = (const float*)d_in[7];
    const float* out_vth    = (const float*)d_in[8];
    const float* out_alpha  = (const float*)d_in[9];
    const float* decode_w   = (const float*)d_in[10];
    const float* decode_b   = (const float*)d_in[11];
    const float* li_norm_w  = (const float*)d_in[12];
    float* out = (float*)d_out;

    size_t off = 0;
    auto alloc = [&](size_t bytes) -> void* {
        void* p = (char*)d_ws + off;
        off += (bytes + 255) & ~(size_t)255;
        return p;
    };
    __bf16* dxA      = (__bf16*)alloc((size_t)Tc * Bc * Dc * 2);   // ping-pong dx
    __bf16* dxB      = (__bf16*)alloc((size_t)Tc * Bc * Dc * 2);
    __bf16* u_tokall = (__bf16*)alloc((size_t)Bc * Sc * UTS * 2);  // [512][4096]
    float*  h_tok    = (float*) alloc((size_t)Bc * Sc * Dc * 4);
    __bf16* xtok     = (__bf16*)alloc((size_t)Bc * Sc * Dc * 2);
    __bf16* wT_in    = (__bf16*)alloc((size_t)NLc * Dc * Dc * 2);
    __bf16* emb_bf   = (__bf16*)alloc((size_t)Vc * Dc * 2);
    __bf16* decw_bf  = (__bf16*)alloc((size_t)Dc * Dc * 2);
    __bf16* decoded  = (__bf16*)alloc((size_t)Bc * Sc * Dc * 2);
    float*  h2       = (float*) alloc((size_t)Bc * Sc * Dc * 4);
    __bf16* h2n      = (__bf16*)alloc((size_t)Bc * Sc * Dc * 2);
    int*    flags    = (int*)   alloc(((size_t)NLc * NPANEL + 64) * 4);
    int*    dirtyAny = flags + NLc * NPANEL;   // flags[512]

    // 1. fused prep (W_in transpose+cast, decw cast, token rows, flags)
    prep<<<5120, 256, 0, stream>>>(W_in, embed, decode_w, token_ids, out_norm_w,
                                   wT_in, decw_bf, xtok, h_tok, flags);

    // 2. u-GEMM (512 blocks, 32x32 MFMA) co-tenant with embed cast (3072 blks)
    gemm_u_cast<<<512 + Vc * Dc / 8 / 256, 256, 0, stream>>>(
        xtok, wT_in, u_tokall, embed, emb_bf);

    // 3a. speculative whole-network scan (flags + decoded, clean assumption)
    spec_scan<<<NPANEL, 1024, 0, stream>>>(
        u_tokall, layer_beta, layer_vth, h_tok, out_alpha, out_beta, out_vth,
        decoded, flags, dirtyAny);

    // 3b. gated fallback (single-block all-layers) + gated out rewrite
    fallback_layers<<<1, 1024, 0, stream>>>(
        u_tokall, W_in, W_out, layer_beta, layer_vth, dxA, dxB, flags, dirtyAny);
    out_scan2<<<dim3(Sc, Bc), 256, 0, stream>>>(
        h_tok, dxA, token_ids, embed, out_norm_w, out_alpha, out_beta, out_vth,
        flags, decoded, dirtyAny);   // dx after even #layers ends in dxA

    // 4. decode head (16x16 path, 32x64 BK=256 -> 256 blocks)
    gemm_bt<2, 32, 64, 256><<<dim3(Dc / 64, (Bc * Sc) / 32), 256, 0, stream>>>(
        decoded, decw_bf, Bc * Sc, Dc, Dc, h2, nullptr, decode_b);
    rmsnorm_rows<<<Bc * Sc, 256, 0, stream>>>(h2, li_norm_w, h2n);
    // LM head: 64x64 via 32x32 MFMA, BK=128 -> 768 blocks (3/CU)
    gemm32<0, 128><<<dim3(Vc / 64, (Bc * Sc) / 64), 256, 0, stream>>>(
        h2n, emb_bf, Bc * Sc, Vc, Dc, out, nullptr);
}